// Round 9
// baseline (138.999 us; speedup 1.0000x reference)
//
#include <hip/hip_runtime.h>
#include <math.h>

// KNN (weights='distance'): B=1024 queries, N=100000 train, D=64, K=16, 10 classes.
// s-domain trick: s = dot - t2/2 computed ENTIRELY in MFMA (C-init = -t2/2).
// Bigger s = closer. K0 cvt+norms | K1 sample (top-4/lane) | K2 theta_s |
// K3 filter s>=theta -> (idx,s) slots | K4 rank top-48 -> exact rescore -> vote.

constexpr int D        = 64;
constexpr int K        = 16;
constexpr int NCLS     = 10;
constexpr int CHUNKLEN = 1024;   // points per filter chunk; wave owns 256 (16 groups)
constexpr int NCHUNK   = 98;     // 98*1024 = 100352 >= 100000
constexpr int NPAD     = NCHUNK * CHUNKLEN;       // 100352, pad rows get -INF score
constexpr int NSUB     = 64;     // sample subchunks
constexpr int SUBLEN   = 128;    // sample points per subchunk (8192 total)
constexpr int SLOT     = 16;     // pair slots per (query, chunk); avg fill ~2
constexpr int MSEL     = 48;     // approx candidates kept for exact rescore

typedef __attribute__((ext_vector_type(8))) short bf16x8_t;
typedef __attribute__((ext_vector_type(4))) float f32x4_t;
typedef unsigned short ushort_t;

__device__ __forceinline__ ushort_t f32_to_bf16_rne(float f) {
  unsigned int u = __float_as_uint(f);
  unsigned int r = u + 0x7FFFu + ((u >> 16) & 1u);
  return (ushort_t)(r >> 16);
}

__device__ __forceinline__ bf16x8_t pack_bf16x8(float4 a, float4 b) {
  union { ushort_t u[8]; bf16x8_t v; } r;
  r.u[0] = f32_to_bf16_rne(a.x); r.u[1] = f32_to_bf16_rne(a.y);
  r.u[2] = f32_to_bf16_rne(a.z); r.u[3] = f32_to_bf16_rne(a.w);
  r.u[4] = f32_to_bf16_rne(b.x); r.u[5] = f32_to_bf16_rne(b.y);
  r.u[6] = f32_to_bf16_rne(b.z); r.u[7] = f32_to_bf16_rne(b.w);
  return r.v;
}

// ---- K0: train fp32 -> bf16; t2 (fp32, for exact rescore); nt2h = -t2/2
//      (MFMA C-init). Pad rows [N,NPAD): tb=0, t2=INF, nt2h=-INF. ----
__global__ __launch_bounds__(256) void cvt_train(
    const float* __restrict__ t, ushort_t* __restrict__ tb,
    float* __restrict__ t2, float* __restrict__ nt2h, int N)
{
  int gid = blockIdx.x * 256 + threadIdx.x;
  int row = gid >> 2, qt = gid & 3;
  if (row >= NPAD) return;
  ushort_t* dst = tb + (size_t)row * D + qt * 16;
  if (row >= N) {
    uint2 z = make_uint2(0u, 0u);
    #pragma unroll
    for (int i = 0; i < 4; ++i) *reinterpret_cast<uint2*>(dst + i * 4) = z;
    if (qt == 0) { t2[row] = INFINITY; nt2h[row] = -INFINITY; }
    return;
  }
  const float* src = t + (size_t)row * D + qt * 16;
  float nrm = 0.f;
  #pragma unroll
  for (int i = 0; i < 4; ++i) {
    float4 v = *reinterpret_cast<const float4*>(src + i * 4);
    nrm = fmaf(v.x, v.x, nrm); nrm = fmaf(v.y, v.y, nrm);
    nrm = fmaf(v.z, v.z, nrm); nrm = fmaf(v.w, v.w, nrm);
    uint2 hh = make_uint2(
      (unsigned)f32_to_bf16_rne(v.x) | ((unsigned)f32_to_bf16_rne(v.y) << 16),
      (unsigned)f32_to_bf16_rne(v.z) | ((unsigned)f32_to_bf16_rne(v.w) << 16));
    *reinterpret_cast<uint2*>(dst + i * 4) = hh;
  }
  nrm += __shfl_xor(nrm, 1);
  nrm += __shfl_xor(nrm, 2);
  if (qt == 0) { t2[row] = nrm; nt2h[row] = -0.5f * nrm; }
}

// ---- K1: sample. grid (B/64, NSUB). Wave w: queries w*16..+16 over 128 pts
//      (8 groups, unroll-4 pipelined). Lane keeps top-4 LARGEST s. ----
__global__ __launch_bounds__(256) void knn_sample(
    const ushort_t* __restrict__ tb, const float* __restrict__ x,
    const float* __restrict__ nt2h, float* __restrict__ samp)
{
  const int tid = threadIdx.x;
  const int w = tid >> 6, lane = tid & 63;
  const int lh = lane & 15, lg = lane >> 4;
  const int qb = blockIdx.x, sub = blockIdx.y;
  const int q = qb * 64 + w * 16 + lh;

  const float* xrp = x + (size_t)q * D + lg * 8;
  bf16x8_t B0 = pack_bf16x8(*reinterpret_cast<const float4*>(xrp),
                            *reinterpret_cast<const float4*>(xrp + 4));
  bf16x8_t B1 = pack_bf16x8(*reinterpret_cast<const float4*>(xrp + 32),
                            *reinterpret_cast<const float4*>(xrp + 36));

  float Ld[4] = {-INFINITY, -INFINITY, -INFINITY, -INFINITY};  // descending

  const int pstart = sub * SUBLEN;
  const ushort_t* abase = tb + (size_t)pstart * D + lh * D + lg * 8;
  const float* nbase = nt2h + pstart + lg * 4;

  bf16x8_t A0[4], A1[4]; float4 NH[4];
  #pragma unroll
  for (int j = 0; j < 4; ++j) {
    const ushort_t* ap = abase + (size_t)j * 16 * D;
    A0[j] = *reinterpret_cast<const bf16x8_t*>(ap);
    A1[j] = *reinterpret_cast<const bf16x8_t*>(ap + 32);
    NH[j] = *reinterpret_cast<const float4*>(nbase + j * 16);
  }
  bf16x8_t N0[4], N1[4]; float4 NN[4];
  #pragma unroll
  for (int j = 0; j < 4; ++j) {
    const ushort_t* ap = abase + (size_t)(4 + j) * 16 * D;
    N0[j] = *reinterpret_cast<const bf16x8_t*>(ap);
    N1[j] = *reinterpret_cast<const bf16x8_t*>(ap + 32);
    NN[j] = *reinterpret_cast<const float4*>(nbase + (4 + j) * 16);
  }

  #pragma unroll
  for (int j = 0; j < 4; ++j) {
    f32x4_t c = {NH[j].x, NH[j].y, NH[j].z, NH[j].w};
    c = __builtin_amdgcn_mfma_f32_16x16x32_bf16(A0[j], B0, c, 0, 0, 0);
    c = __builtin_amdgcn_mfma_f32_16x16x32_bf16(A1[j], B1, c, 0, 0, 0);
    #pragma unroll
    for (int r = 0; r < 4; ++r) {
      float sv = c[r];
      if (sv > Ld[3]) {
        Ld[3] = sv;
        if (Ld[3] > Ld[2]) { float s_ = Ld[3]; Ld[3] = Ld[2]; Ld[2] = s_; }
        if (Ld[2] > Ld[1]) { float s_ = Ld[2]; Ld[2] = Ld[1]; Ld[1] = s_; }
        if (Ld[1] > Ld[0]) { float s_ = Ld[1]; Ld[1] = Ld[0]; Ld[0] = s_; }
      }
    }
  }
  #pragma unroll
  for (int j = 0; j < 4; ++j) {
    f32x4_t c = {NN[j].x, NN[j].y, NN[j].z, NN[j].w};
    c = __builtin_amdgcn_mfma_f32_16x16x32_bf16(N0[j], B0, c, 0, 0, 0);
    c = __builtin_amdgcn_mfma_f32_16x16x32_bf16(N1[j], B1, c, 0, 0, 0);
    #pragma unroll
    for (int r = 0; r < 4; ++r) {
      float sv = c[r];
      if (sv > Ld[3]) {
        Ld[3] = sv;
        if (Ld[3] > Ld[2]) { float s_ = Ld[3]; Ld[3] = Ld[2]; Ld[2] = s_; }
        if (Ld[2] > Ld[1]) { float s_ = Ld[2]; Ld[2] = Ld[1]; Ld[1] = s_; }
        if (Ld[1] > Ld[0]) { float s_ = Ld[1]; Ld[1] = Ld[0]; Ld[0] = s_; }
      }
    }
  }

  float* outp = samp + (size_t)q * (NSUB * 16) + sub * 16 + lg * 4;
  *reinterpret_cast<float4*>(outp) = make_float4(Ld[0], Ld[1], Ld[2], Ld[3]);
}

// ---- K2: one wave/query: 64 lanes x 4 descending-4 runs; 16 rounds of
//      wave-max pop; theta = 16th popped (tie multi-pop only loosens). ----
__global__ __launch_bounds__(256) void knn_theta(
    const float* __restrict__ samp, float* __restrict__ theta, int B)
{
  const int w = threadIdx.x >> 6, lane = threadIdx.x & 63;
  const int q = blockIdx.x * 4 + w;
  if (q >= B) return;

  const float* s = samp + (size_t)q * (NSUB * 16) + lane * 16;
  float4 p0 = *reinterpret_cast<const float4*>(s);
  float4 p1 = *reinterpret_cast<const float4*>(s + 4);
  float4 p2 = *reinterpret_cast<const float4*>(s + 8);
  float4 p3 = *reinterpret_cast<const float4*>(s + 12);
  float L0[4] = {p0.x, p0.y, p0.z, p0.w};
  float L1[4] = {p1.x, p1.y, p1.z, p1.w};
  float L2[4] = {p2.x, p2.y, p2.z, p2.w};
  float L3[4] = {p3.x, p3.y, p3.z, p3.w};

  float th = -INFINITY;
  for (int r = 0; r < K; ++r) {
    float bd = fmaxf(fmaxf(L0[0], L1[0]), fmaxf(L2[0], L3[0]));
    #pragma unroll
    for (int sdx = 0; sdx < 6; ++sdx) bd = fmaxf(bd, __shfl_xor(bd, 32 >> sdx));
    if (L0[0] == bd) { L0[0] = L0[1]; L0[1] = L0[2]; L0[2] = L0[3]; L0[3] = -INFINITY; }
    if (L1[0] == bd) { L1[0] = L1[1]; L1[1] = L1[2]; L1[2] = L1[3]; L1[3] = -INFINITY; }
    if (L2[0] == bd) { L2[0] = L2[1]; L2[1] = L2[2]; L2[2] = L2[3]; L2[3] = -INFINITY; }
    if (L3[0] == bd) { L3[0] = L3[1]; L3[1] = L3[2]; L3[2] = L3[3]; L3[3] = -INFINITY; }
    th = bd;
  }
  if (lane == 0) theta[q] = th;
}

// ---- K3: filter. grid (B/64, NCHUNK), 4 waves; wave owns 256 pts (16 groups,
//      unroll-4, prefetch 4 ahead). s from MFMA only; accept s >= theta. ----
__global__ __launch_bounds__(256) void knn_filter(
    const ushort_t* __restrict__ tb, const float* __restrict__ x,
    const float* __restrict__ nt2h, const float* __restrict__ theta,
    int* __restrict__ cnts, int2* __restrict__ cand2)
{
  __shared__ int  cnt_l[64];
  __shared__ int2 list_p[64][SLOT];   // 8 KB

  const int tid = threadIdx.x;
  const int w = tid >> 6, lane = tid & 63;
  const int lh = lane & 15, lg = lane >> 4;
  const int qb = blockIdx.x, ch = blockIdx.y;
  const int q0 = qb * 64;
  const int wp0 = ch * CHUNKLEN + w * (CHUNKLEN / 4);

  if (tid < 64) cnt_l[tid] = 0;
  __syncthreads();

  bf16x8_t Bq0[4], Bq1[4];
  float th[4];
  #pragma unroll
  for (int ct = 0; ct < 4; ++ct) {
    const float* xrp = x + (size_t)(q0 + ct * 16 + lh) * D + lg * 8;
    Bq0[ct] = pack_bf16x8(*reinterpret_cast<const float4*>(xrp),
                          *reinterpret_cast<const float4*>(xrp + 4));
    Bq1[ct] = pack_bf16x8(*reinterpret_cast<const float4*>(xrp + 32),
                          *reinterpret_cast<const float4*>(xrp + 36));
    th[ct] = theta[q0 + ct * 16 + lh];
  }

  const ushort_t* abase = tb + (size_t)wp0 * D + lh * D + lg * 8;
  const float* nbase = nt2h + wp0 + lg * 4;

  bf16x8_t A0[4], A1[4]; float4 NH[4];
  #pragma unroll
  for (int j = 0; j < 4; ++j) {
    const ushort_t* ap = abase + (size_t)j * 16 * D;
    A0[j] = *reinterpret_cast<const bf16x8_t*>(ap);
    A1[j] = *reinterpret_cast<const bf16x8_t*>(ap + 32);
    NH[j] = *reinterpret_cast<const float4*>(nbase + j * 16);
  }

  #define PROCESS(A0_, A1_, NH_, GIDX_)                                           \
    {                                                                             \
      const int pg = wp0 + (GIDX_) * 16 + lg * 4;                                 \
      _Pragma("unroll")                                                           \
      for (int ct = 0; ct < 4; ++ct) {                                            \
        f32x4_t c = {NH_.x, NH_.y, NH_.z, NH_.w};                                 \
        c = __builtin_amdgcn_mfma_f32_16x16x32_bf16(A0_, Bq0[ct], c, 0, 0, 0);    \
        c = __builtin_amdgcn_mfma_f32_16x16x32_bf16(A1_, Bq1[ct], c, 0, 0, 0);    \
        unsigned m = (c[0] >= th[ct] ? 1u : 0u) | (c[1] >= th[ct] ? 2u : 0u)      \
                   | (c[2] >= th[ct] ? 4u : 0u) | (c[3] >= th[ct] ? 8u : 0u);     \
        if (m) {                                                                  \
          const int qloc = ct * 16 + lh;                                          \
          int n = __popc(m);                                                      \
          int base = atomicAdd(&cnt_l[qloc], n);                                  \
          while (m) {                                                             \
            int r = __ffs(m) - 1; m &= m - 1;                                     \
            float sv = (r == 0) ? c[0] : (r == 1) ? c[1] : (r == 2) ? c[2] : c[3];\
            if (base < SLOT)                                                      \
              list_p[qloc][base] = make_int2(pg + r, __float_as_int(sv));         \
            ++base;                                                               \
          }                                                                       \
        }                                                                         \
      }                                                                           \
    }

  for (int it = 0; it < 4; ++it) {
    bf16x8_t N0[4], N1[4]; float4 NN[4];
    if (it < 3) {
      #pragma unroll
      for (int j = 0; j < 4; ++j) {
        const int gi = (it + 1) * 4 + j;
        const ushort_t* ap = abase + (size_t)gi * 16 * D;
        N0[j] = *reinterpret_cast<const bf16x8_t*>(ap);
        N1[j] = *reinterpret_cast<const bf16x8_t*>(ap + 32);
        NN[j] = *reinterpret_cast<const float4*>(nbase + gi * 16);
      }
    }
    PROCESS(A0[0], A1[0], NH[0], it * 4 + 0);
    PROCESS(A0[1], A1[1], NH[1], it * 4 + 1);
    PROCESS(A0[2], A1[2], NH[2], it * 4 + 2);
    PROCESS(A0[3], A1[3], NH[3], it * 4 + 3);
    if (it < 3) {
      #pragma unroll
      for (int j = 0; j < 4; ++j) { A0[j] = N0[j]; A1[j] = N1[j]; NH[j] = NN[j]; }
    }
  }
  #undef PROCESS

  __syncthreads();
  if (tid < 64) {
    int n = cnt_l[tid]; if (n > SLOT) n = SLOT;
    size_t o = (size_t)(q0 + tid) * NCHUNK + ch;
    cnts[o] = n;
    for (int j = 0; j < n; ++j) cand2[o * SLOT + j] = list_p[tid][j];
  }
}

// ---- K4: one block per query. Compact (idx,s) pairs, rank-by-count in
//      s-descending order -> top-MSEL, exact fp32 rescore, top-16, vote. ----
__global__ __launch_bounds__(256) void knn_vote(
    const float* __restrict__ x, const float* __restrict__ train,
    const float* __restrict__ t2, const int* __restrict__ labels,
    const int* __restrict__ cnts, const int2* __restrict__ cand2,
    float* __restrict__ out, int B, int N)
{
  __shared__ int2  cpair[NCHUNK * SLOT];   // 1568 pairs = 12.25 KB
  __shared__ float sortd[MSEL];
  __shared__ int   sorti[MSEL];
  __shared__ float xs[D];
  __shared__ int   total_s;
  __shared__ float x2_s;

  const int tid = threadIdx.x;
  const int w = tid >> 6, lane = tid & 63;
  const int q = blockIdx.x;

  if (tid == 0) total_s = 0;
  if (tid < D) xs[tid] = x[(size_t)q * D + tid];
  if (tid < MSEL) { sortd[tid] = INFINITY; sorti[tid] = 0x7fffffff; }
  __syncthreads();

  if (w == 0) {
    float v = xs[lane];
    float s = v * v;
    #pragma unroll
    for (int o = 32; o > 0; o >>= 1) s += __shfl_xor(s, o);
    if (lane == 0) x2_s = s;
  }
  if (tid < NCHUNK) {
    int n = cnts[(size_t)q * NCHUNK + tid];
    int base = atomicAdd(&total_s, n);
    const int2* src = cand2 + ((size_t)q * NCHUNK + tid) * SLOT;
    for (int j = 0; j < n; ++j) cpair[base + j] = src[j];
  }
  __syncthreads();

  const int total = total_s;     // typically ~196, >= 16 guaranteed
  const float x2 = x2_s;

  // rank-by-count in (s desc, idx asc) lex order; idx unique -> total order
  for (int j = tid; j < total; j += 256) {
    int2 mine = cpair[j];
    float ms = __int_as_float(mine.y);
    int   mi = mine.x;
    int rank = 0;
    for (int k = 0; k < total; ++k) {
      int2 o = cpair[k];
      float os = __int_as_float(o.y);
      rank += (os > ms || (os == ms && o.x < mi)) ? 1 : 0;
    }
    if (rank < MSEL) { sortd[rank] = ms; sorti[rank] = mi; }
  }
  __syncthreads();

  // exact fp32 rescore of the MSEL approx-best
  if (tid < MSEL) {
    int idx = sorti[tid];
    float d2v = INFINITY;
    if (idx != 0x7fffffff) {
      const float* tr = train + (size_t)idx * D;
      float dot = 0.f;
      #pragma unroll
      for (int i = 0; i < 16; ++i) {
        float4 tv = *reinterpret_cast<const float4*>(tr + i * 4);
        dot = fmaf(xs[i * 4 + 0], tv.x, dot); dot = fmaf(xs[i * 4 + 1], tv.y, dot);
        dot = fmaf(xs[i * 4 + 2], tv.z, dot); dot = fmaf(xs[i * 4 + 3], tv.w, dot);
      }
      d2v = fmaxf(x2 - 2.f * dot + t2[idx], 0.f);
    }
    sortd[tid] = d2v;   // overwrite approx with exact
  }
  __syncthreads();

  if (w == 0) {
    float vd = (lane < MSEL) ? sortd[lane] : INFINITY;
    int   vi = (lane < MSEL) ? sorti[lane] : 0x7fffffff;
    float myD = INFINITY; int myI = 0;
    for (int r = 0; r < K; ++r) {      // exact (d2,idx)-lex top-16
      float bd = vd; int bi = vi;
      #pragma unroll
      for (int s = 0; s < 6; ++s) {
        int off = 32 >> s;
        float od = __shfl_xor(bd, off);
        int   oi = __shfl_xor(bi, off);
        if (od < bd || (od == bd && oi < bi)) { bd = od; bi = oi; }
      }
      if (vd == bd && vi == bi) { vd = INFINITY; vi = 0x7fffffff; }
      if (lane == r) { myD = bd; myI = bi; }
    }

    int valid = (lane < K) && (myD < INFINITY) && (myI < N);
    float dist = sqrtf(fmaxf(myD, 0.f));
    int lab = labels[(valid && myI < N) ? myI : 0];
    int isz = (valid && dist == 0.f) ? 1 : 0;
    float wgt = 1.f / dist;

    float accw[NCLS]; float acci[NCLS]; int anyInf = 0;
    #pragma unroll
    for (int c = 0; c < NCLS; ++c) { accw[c] = 0.f; acci[c] = 0.f; }
    for (int r = 0; r < K; ++r) {
      int   vr   = __shfl(valid, r);
      int   labr = __shfl(lab, r);
      float wgtr = __shfl(wgt, r);
      int   iszr = __shfl(isz, r);
      if (vr) {
        anyInf |= iszr;
        #pragma unroll
        for (int c = 0; c < NCLS; ++c) {
          accw[c] += (labr == c) ? wgtr : 0.f;
          acci[c] += (labr == c && iszr) ? 1.f : 0.f;
        }
      }
    }

    if (lane == 0) {
      float proba[NCLS]; float s = 0.f;
      #pragma unroll
      for (int c = 0; c < NCLS; ++c) { proba[c] = anyInf ? acci[c] : accw[c]; s += proba[c]; }
      if (s == 0.f) s = 1.f;
      #pragma unroll
      for (int c = 0; c < NCLS; ++c) proba[c] = proba[c] / s;
      int best = 0; float bv = proba[0];
      #pragma unroll
      for (int c = 1; c < NCLS; ++c) if (proba[c] > bv) { bv = proba[c]; best = c; }
      out[q] = (float)best;
      #pragma unroll
      for (int c = 0; c < NCLS; ++c) out[B + q * NCLS + c] = proba[c];
    }
  }
}

extern "C" void kernel_launch(void* const* d_in, const int* in_sizes, int n_in,
                              void* d_out, int out_size, void* d_ws, size_t ws_size,
                              hipStream_t stream)
{
  const float* x      = (const float*)d_in[0];
  const float* train  = (const float*)d_in[1];
  const int*   labels = (const int*)d_in[2];
  float* out = (float*)d_out;

  const int B = in_sizes[0] / D;   // 1024
  const int N = in_sizes[2];       // 100000

  // workspace carve (16B-aligned), ~27 MB total; samp ALIASES cand2 (sample/
  // theta finish before filter writes cand2 -- stream-ordered).
  char* ws = (char*)d_ws;
  size_t off = 0;
  ushort_t* train_bf = (ushort_t*)(ws + off); off += (size_t)NPAD * D * 2;           // 12.85 MB
  float*    t2       = (float*)(ws + off);    off += (size_t)NPAD * 4;               // 401 KB
  float*    nt2h     = (float*)(ws + off);    off += (size_t)NPAD * 4;               // 401 KB
  float*    theta    = (float*)(ws + off);    off += (size_t)B * 4;
  int*      cnts     = (int*)(ws + off);      off += (size_t)B * NCHUNK * 4;         // 401 KB
  int2*     cand2    = (int2*)(ws + off);     off += (size_t)B * NCHUNK * SLOT * 8;  // 12.85 MB
  float*    samp     = (float*)cand2;         // B*NSUB*16*4 = 4 MB <= cand2 region

  cvt_train<<<(NPAD * 4 + 255) / 256, 256, 0, stream>>>(train, train_bf, t2, nt2h, N);
  knn_sample<<<dim3(B / 64, NSUB), 256, 0, stream>>>(train_bf, x, nt2h, samp);
  knn_theta<<<(B + 3) / 4, 256, 0, stream>>>(samp, theta, B);
  knn_filter<<<dim3(B / 64, NCHUNK), 256, 0, stream>>>(train_bf, x, nt2h, theta, cnts, cand2);
  knn_vote<<<B, 256, 0, stream>>>(x, train, t2, labels, cnts, cand2, out, B, N);
}

// Round 10
// 116.827 us; speedup vs baseline: 1.1898x; 1.1898x over previous
//
#include <hip/hip_runtime.h>
#include <math.h>

// KNN (weights='distance'): B=1024 queries, N=100000 train, D=64, K=16, 10 classes.
// s-domain: s = dot - t2/2 computed entirely in MFMA (C-init = -t2/2); bigger=closer.
// K0 cvt+norms | K1 sample 8192 (top-4/lane) | K2 theta_s | K3 filter (depth-2
// prefetch, XCD-swizzled so same-chunk blocks share one L2) | K4 rank->rescore->vote.

constexpr int D        = 64;
constexpr int K        = 16;
constexpr int NCLS     = 10;
constexpr int CHUNKLEN = 896;    // points per filter chunk; wave owns 224 (14 groups)
constexpr int NCHUNK   = 112;    // 112*896 = 100352 >= 100000; divisible by 8 (XCD swizzle)
constexpr int NPAD     = NCHUNK * CHUNKLEN + 32;  // 100384 (prefetch overrun room)
constexpr int NSUB     = 64;     // sample subchunks
constexpr int SUBLEN   = 128;    // sample points per subchunk (8192 total)
constexpr int SLOT     = 16;     // pair slots per (query, chunk); avg fill ~1.75
constexpr int MSEL     = 48;     // approx candidates kept for exact rescore

typedef __attribute__((ext_vector_type(8))) short bf16x8_t;
typedef __attribute__((ext_vector_type(4))) float f32x4_t;
typedef unsigned short ushort_t;

__device__ __forceinline__ ushort_t f32_to_bf16_rne(float f) {
  unsigned int u = __float_as_uint(f);
  unsigned int r = u + 0x7FFFu + ((u >> 16) & 1u);
  return (ushort_t)(r >> 16);
}

__device__ __forceinline__ bf16x8_t pack_bf16x8(float4 a, float4 b) {
  union { ushort_t u[8]; bf16x8_t v; } r;
  r.u[0] = f32_to_bf16_rne(a.x); r.u[1] = f32_to_bf16_rne(a.y);
  r.u[2] = f32_to_bf16_rne(a.z); r.u[3] = f32_to_bf16_rne(a.w);
  r.u[4] = f32_to_bf16_rne(b.x); r.u[5] = f32_to_bf16_rne(b.y);
  r.u[6] = f32_to_bf16_rne(b.z); r.u[7] = f32_to_bf16_rne(b.w);
  return r.v;
}

// ---- K0: train fp32 -> bf16; t2 (exact rescore); nt2h = -t2/2 (MFMA C-init).
//      Pad rows [N,NPAD): tb=0, t2=INF, nt2h=-INF (never accepted). ----
__global__ __launch_bounds__(256) void cvt_train(
    const float* __restrict__ t, ushort_t* __restrict__ tb,
    float* __restrict__ t2, float* __restrict__ nt2h, int N)
{
  int gid = blockIdx.x * 256 + threadIdx.x;
  int row = gid >> 2, qt = gid & 3;
  if (row >= NPAD) return;
  ushort_t* dst = tb + (size_t)row * D + qt * 16;
  if (row >= N) {
    uint2 z = make_uint2(0u, 0u);
    #pragma unroll
    for (int i = 0; i < 4; ++i) *reinterpret_cast<uint2*>(dst + i * 4) = z;
    if (qt == 0) { t2[row] = INFINITY; nt2h[row] = -INFINITY; }
    return;
  }
  const float* src = t + (size_t)row * D + qt * 16;
  float nrm = 0.f;
  #pragma unroll
  for (int i = 0; i < 4; ++i) {
    float4 v = *reinterpret_cast<const float4*>(src + i * 4);
    nrm = fmaf(v.x, v.x, nrm); nrm = fmaf(v.y, v.y, nrm);
    nrm = fmaf(v.z, v.z, nrm); nrm = fmaf(v.w, v.w, nrm);
    uint2 hh = make_uint2(
      (unsigned)f32_to_bf16_rne(v.x) | ((unsigned)f32_to_bf16_rne(v.y) << 16),
      (unsigned)f32_to_bf16_rne(v.z) | ((unsigned)f32_to_bf16_rne(v.w) << 16));
    *reinterpret_cast<uint2*>(dst + i * 4) = hh;
  }
  nrm += __shfl_xor(nrm, 1);
  nrm += __shfl_xor(nrm, 2);
  if (qt == 0) { t2[row] = nrm; nt2h[row] = -0.5f * nrm; }
}

// ---- K1: sample. grid (B/64, NSUB). Wave: 16 queries x 128 pts (8 groups,
//      all preloaded). Lane keeps top-4 LARGEST s. ----
__global__ __launch_bounds__(256) void knn_sample(
    const ushort_t* __restrict__ tb, const float* __restrict__ x,
    const float* __restrict__ nt2h, float* __restrict__ samp)
{
  const int tid = threadIdx.x;
  const int w = tid >> 6, lane = tid & 63;
  const int lh = lane & 15, lg = lane >> 4;
  const int qb = blockIdx.x, sub = blockIdx.y;
  const int q = qb * 64 + w * 16 + lh;

  const float* xrp = x + (size_t)q * D + lg * 8;
  bf16x8_t B0 = pack_bf16x8(*reinterpret_cast<const float4*>(xrp),
                            *reinterpret_cast<const float4*>(xrp + 4));
  bf16x8_t B1 = pack_bf16x8(*reinterpret_cast<const float4*>(xrp + 32),
                            *reinterpret_cast<const float4*>(xrp + 36));

  float Ld[4] = {-INFINITY, -INFINITY, -INFINITY, -INFINITY};  // descending

  const int pstart = sub * SUBLEN;
  const ushort_t* abase = tb + (size_t)pstart * D + lh * D + lg * 8;
  const float* nbase = nt2h + pstart + lg * 4;

  bf16x8_t A0[4], A1[4]; float4 NH[4];
  #pragma unroll
  for (int j = 0; j < 4; ++j) {
    const ushort_t* ap = abase + (size_t)j * 16 * D;
    A0[j] = *reinterpret_cast<const bf16x8_t*>(ap);
    A1[j] = *reinterpret_cast<const bf16x8_t*>(ap + 32);
    NH[j] = *reinterpret_cast<const float4*>(nbase + j * 16);
  }
  bf16x8_t N0[4], N1[4]; float4 NN[4];
  #pragma unroll
  for (int j = 0; j < 4; ++j) {
    const ushort_t* ap = abase + (size_t)(4 + j) * 16 * D;
    N0[j] = *reinterpret_cast<const bf16x8_t*>(ap);
    N1[j] = *reinterpret_cast<const bf16x8_t*>(ap + 32);
    NN[j] = *reinterpret_cast<const float4*>(nbase + (4 + j) * 16);
  }

  #pragma unroll
  for (int j = 0; j < 4; ++j) {
    f32x4_t c = {NH[j].x, NH[j].y, NH[j].z, NH[j].w};
    c = __builtin_amdgcn_mfma_f32_16x16x32_bf16(A0[j], B0, c, 0, 0, 0);
    c = __builtin_amdgcn_mfma_f32_16x16x32_bf16(A1[j], B1, c, 0, 0, 0);
    #pragma unroll
    for (int r = 0; r < 4; ++r) {
      float sv = c[r];
      if (sv > Ld[3]) {
        Ld[3] = sv;
        if (Ld[3] > Ld[2]) { float s_ = Ld[3]; Ld[3] = Ld[2]; Ld[2] = s_; }
        if (Ld[2] > Ld[1]) { float s_ = Ld[2]; Ld[2] = Ld[1]; Ld[1] = s_; }
        if (Ld[1] > Ld[0]) { float s_ = Ld[1]; Ld[1] = Ld[0]; Ld[0] = s_; }
      }
    }
  }
  #pragma unroll
  for (int j = 0; j < 4; ++j) {
    f32x4_t c = {NN[j].x, NN[j].y, NN[j].z, NN[j].w};
    c = __builtin_amdgcn_mfma_f32_16x16x32_bf16(N0[j], B0, c, 0, 0, 0);
    c = __builtin_amdgcn_mfma_f32_16x16x32_bf16(N1[j], B1, c, 0, 0, 0);
    #pragma unroll
    for (int r = 0; r < 4; ++r) {
      float sv = c[r];
      if (sv > Ld[3]) {
        Ld[3] = sv;
        if (Ld[3] > Ld[2]) { float s_ = Ld[3]; Ld[3] = Ld[2]; Ld[2] = s_; }
        if (Ld[2] > Ld[1]) { float s_ = Ld[2]; Ld[2] = Ld[1]; Ld[1] = s_; }
        if (Ld[1] > Ld[0]) { float s_ = Ld[1]; Ld[1] = Ld[0]; Ld[0] = s_; }
      }
    }
  }

  float* outp = samp + (size_t)q * (NSUB * 16) + sub * 16 + lg * 4;
  *reinterpret_cast<float4*>(outp) = make_float4(Ld[0], Ld[1], Ld[2], Ld[3]);
}

// ---- K2: one wave/query: 64 lanes x 4 descending-4 runs; 16 rounds of
//      wave-max pop; theta = 16th popped (tie multi-pop only loosens). ----
__global__ __launch_bounds__(256) void knn_theta(
    const float* __restrict__ samp, float* __restrict__ theta, int B)
{
  const int w = threadIdx.x >> 6, lane = threadIdx.x & 63;
  const int q = blockIdx.x * 4 + w;
  if (q >= B) return;

  const float* s = samp + (size_t)q * (NSUB * 16) + lane * 16;
  float4 p0 = *reinterpret_cast<const float4*>(s);
  float4 p1 = *reinterpret_cast<const float4*>(s + 4);
  float4 p2 = *reinterpret_cast<const float4*>(s + 8);
  float4 p3 = *reinterpret_cast<const float4*>(s + 12);
  float L0[4] = {p0.x, p0.y, p0.z, p0.w};
  float L1[4] = {p1.x, p1.y, p1.z, p1.w};
  float L2[4] = {p2.x, p2.y, p2.z, p2.w};
  float L3[4] = {p3.x, p3.y, p3.z, p3.w};

  float th = -INFINITY;
  for (int r = 0; r < K; ++r) {
    float bd = fmaxf(fmaxf(L0[0], L1[0]), fmaxf(L2[0], L3[0]));
    #pragma unroll
    for (int sdx = 0; sdx < 6; ++sdx) bd = fmaxf(bd, __shfl_xor(bd, 32 >> sdx));
    if (L0[0] == bd) { L0[0] = L0[1]; L0[1] = L0[2]; L0[2] = L0[3]; L0[3] = -INFINITY; }
    if (L1[0] == bd) { L1[0] = L1[1]; L1[1] = L1[2]; L1[2] = L1[3]; L1[3] = -INFINITY; }
    if (L2[0] == bd) { L2[0] = L2[1]; L2[1] = L2[2]; L2[2] = L2[3]; L2[3] = -INFINITY; }
    if (L3[0] == bd) { L3[0] = L3[1]; L3[1] = L3[2]; L3[2] = L3[3]; L3[3] = -INFINITY; }
    th = bd;
  }
  if (lane == 0) theta[q] = th;
}

// ---- K3: filter. grid (16, NCHUNK) XCD-SWIZZLED: logical (qb,ch) derived so
//      all 16 blocks of a chunk land on XCD ch%8 (d%8==ch%8, bijective since
//      NCHUNK%8==0) -> chunk is HBM-fetched once into ONE L2. Wave holds
//      B-frags for all 64 queries, owns 224 pts (14 groups, depth-2 prefetch,
//      unroll-2). s from MFMA C-init; accept s >= theta. ----
__global__ __launch_bounds__(256) void knn_filter(
    const ushort_t* __restrict__ tb, const float* __restrict__ x,
    const float* __restrict__ nt2h, const float* __restrict__ theta,
    int* __restrict__ cnts, int2* __restrict__ cand2)
{
  __shared__ int  cnt_l[64];
  __shared__ int2 list_p[64][SLOT];   // 8 KB

  const int tid = threadIdx.x;
  const int w = tid >> 6, lane = tid & 63;
  const int lh = lane & 15, lg = lane >> 4;

  // XCD-aware bijective remap: d = qb' + 16*ch' -> (qb, ch) with ch%8 == d%8
  const int d   = blockIdx.x + 16 * blockIdx.y;   // 0..1791
  const int xcd = d & 7;
  const int t_  = d >> 3;                          // 0..223
  const int qb  = t_ & 15;
  const int ch  = ((t_ >> 4) << 3) | xcd;          // 0..111

  const int q0 = qb * 64;
  const int wp0 = ch * CHUNKLEN + w * (CHUNKLEN / 4);   // wave's 224-pt base

  if (tid < 64) cnt_l[tid] = 0;
  __syncthreads();

  bf16x8_t Bq0[4], Bq1[4];
  float th[4];
  #pragma unroll
  for (int ct = 0; ct < 4; ++ct) {
    const float* xrp = x + (size_t)(q0 + ct * 16 + lh) * D + lg * 8;
    Bq0[ct] = pack_bf16x8(*reinterpret_cast<const float4*>(xrp),
                          *reinterpret_cast<const float4*>(xrp + 4));
    Bq1[ct] = pack_bf16x8(*reinterpret_cast<const float4*>(xrp + 32),
                          *reinterpret_cast<const float4*>(xrp + 36));
    th[ct] = theta[q0 + ct * 16 + lh];
  }

  const ushort_t* abase = tb + (size_t)wp0 * D + lh * D + lg * 8;
  const float* nbase = nt2h + wp0 + lg * 4;

  // two groups in flight + two prefetched (named registers, depth-2)
  bf16x8_t cA0 = *reinterpret_cast<const bf16x8_t*>(abase);
  bf16x8_t cA1 = *reinterpret_cast<const bf16x8_t*>(abase + 32);
  float4   cNA = *reinterpret_cast<const float4*>(nbase);
  bf16x8_t cB0 = *reinterpret_cast<const bf16x8_t*>(abase + (size_t)16 * D);
  bf16x8_t cB1 = *reinterpret_cast<const bf16x8_t*>(abase + (size_t)16 * D + 32);
  float4   cNB = *reinterpret_cast<const float4*>(nbase + 16);

  #define PROCESS(A0_, A1_, NH_, GIDX_)                                           \
    {                                                                             \
      const int pg = wp0 + (GIDX_) * 16 + lg * 4;                                 \
      _Pragma("unroll")                                                           \
      for (int ct = 0; ct < 4; ++ct) {                                            \
        f32x4_t c = {NH_.x, NH_.y, NH_.z, NH_.w};                                 \
        c = __builtin_amdgcn_mfma_f32_16x16x32_bf16(A0_, Bq0[ct], c, 0, 0, 0);    \
        c = __builtin_amdgcn_mfma_f32_16x16x32_bf16(A1_, Bq1[ct], c, 0, 0, 0);    \
        unsigned m = (c[0] >= th[ct] ? 1u : 0u) | (c[1] >= th[ct] ? 2u : 0u)      \
                   | (c[2] >= th[ct] ? 4u : 0u) | (c[3] >= th[ct] ? 8u : 0u);     \
        if (m) {                                                                  \
          const int qloc = ct * 16 + lh;                                          \
          int n = __popc(m);                                                      \
          int base = atomicAdd(&cnt_l[qloc], n);                                  \
          while (m) {                                                             \
            int r = __ffs(m) - 1; m &= m - 1;                                     \
            float sv = (r == 0) ? c[0] : (r == 1) ? c[1] : (r == 2) ? c[2] : c[3];\
            if (base < SLOT)                                                      \
              list_p[qloc][base] = make_int2(pg + r, __float_as_int(sv));         \
            ++base;                                                               \
          }                                                                       \
        }                                                                         \
      }                                                                           \
    }

  for (int g = 0; g < 7; ++g) {   // 7 iters x 2 groups = 14 groups
    const ushort_t* an = abase + (size_t)(2 * g + 2) * 16 * D;
    bf16x8_t nA0 = *reinterpret_cast<const bf16x8_t*>(an);
    bf16x8_t nA1 = *reinterpret_cast<const bf16x8_t*>(an + 32);
    float4   nNA = *reinterpret_cast<const float4*>(nbase + (2 * g + 2) * 16);
    bf16x8_t nB0 = *reinterpret_cast<const bf16x8_t*>(an + (size_t)16 * D);
    bf16x8_t nB1 = *reinterpret_cast<const bf16x8_t*>(an + (size_t)16 * D + 32);
    float4   nNB = *reinterpret_cast<const float4*>(nbase + (2 * g + 3) * 16);

    PROCESS(cA0, cA1, cNA, 2 * g);
    PROCESS(cB0, cB1, cNB, 2 * g + 1);

    cA0 = nA0; cA1 = nA1; cNA = nNA;
    cB0 = nB0; cB1 = nB1; cNB = nNB;
  }
  #undef PROCESS

  __syncthreads();
  if (tid < 64) {
    int n = cnt_l[tid]; if (n > SLOT) n = SLOT;
    size_t o = (size_t)(q0 + tid) * NCHUNK + ch;
    cnts[o] = n;
    for (int j = 0; j < n; ++j) cand2[o * SLOT + j] = list_p[tid][j];
  }
}

// ---- K4: one block per query. Compact (idx,s) pairs, rank-by-count in
//      (s desc, idx asc) -> top-MSEL, exact fp32 rescore, top-16, vote. ----
__global__ __launch_bounds__(256) void knn_vote(
    const float* __restrict__ x, const float* __restrict__ train,
    const float* __restrict__ t2, const int* __restrict__ labels,
    const int* __restrict__ cnts, const int2* __restrict__ cand2,
    float* __restrict__ out, int B, int N)
{
  __shared__ int2  cpair[NCHUNK * SLOT];   // 1792 pairs = 14 KB
  __shared__ float sortd[MSEL];
  __shared__ int   sorti[MSEL];
  __shared__ float xs[D];
  __shared__ int   total_s;
  __shared__ float x2_s;

  const int tid = threadIdx.x;
  const int w = tid >> 6, lane = tid & 63;
  const int q = blockIdx.x;

  if (tid == 0) total_s = 0;
  if (tid < D) xs[tid] = x[(size_t)q * D + tid];
  if (tid < MSEL) { sortd[tid] = INFINITY; sorti[tid] = 0x7fffffff; }
  __syncthreads();

  if (w == 0) {
    float v = xs[lane];
    float s = v * v;
    #pragma unroll
    for (int o = 32; o > 0; o >>= 1) s += __shfl_xor(s, o);
    if (lane == 0) x2_s = s;
  }
  if (tid < NCHUNK) {
    int n = cnts[(size_t)q * NCHUNK + tid];
    int base = atomicAdd(&total_s, n);
    const int2* src = cand2 + ((size_t)q * NCHUNK + tid) * SLOT;
    for (int j = 0; j < n; ++j) cpair[base + j] = src[j];
  }
  __syncthreads();

  const int total = total_s;     // typically ~196, >= 16 guaranteed
  const float x2 = x2_s;

  // rank-by-count in (s desc, idx asc) lex order; idx unique -> total order
  for (int j = tid; j < total; j += 256) {
    int2 mine = cpair[j];
    float ms = __int_as_float(mine.y);
    int   mi = mine.x;
    int rank = 0;
    for (int k = 0; k < total; ++k) {
      int2 o = cpair[k];
      float os = __int_as_float(o.y);
      rank += (os > ms || (os == ms && o.x < mi)) ? 1 : 0;
    }
    if (rank < MSEL) { sortd[rank] = ms; sorti[rank] = mi; }
  }
  __syncthreads();

  // exact fp32 rescore of the MSEL approx-best
  if (tid < MSEL) {
    int idx = sorti[tid];
    float d2v = INFINITY;
    if (idx != 0x7fffffff) {
      const float* tr = train + (size_t)idx * D;
      float dot = 0.f;
      #pragma unroll
      for (int i = 0; i < 16; ++i) {
        float4 tv = *reinterpret_cast<const float4*>(tr + i * 4);
        dot = fmaf(xs[i * 4 + 0], tv.x, dot); dot = fmaf(xs[i * 4 + 1], tv.y, dot);
        dot = fmaf(xs[i * 4 + 2], tv.z, dot); dot = fmaf(xs[i * 4 + 3], tv.w, dot);
      }
      d2v = fmaxf(x2 - 2.f * dot + t2[idx], 0.f);
    }
    sortd[tid] = d2v;   // overwrite approx with exact
  }
  __syncthreads();

  if (w == 0) {
    float vd = (lane < MSEL) ? sortd[lane] : INFINITY;
    int   vi = (lane < MSEL) ? sorti[lane] : 0x7fffffff;
    float myD = INFINITY; int myI = 0;
    for (int r = 0; r < K; ++r) {      // exact (d2,idx)-lex top-16
      float bd = vd; int bi = vi;
      #pragma unroll
      for (int s = 0; s < 6; ++s) {
        int off = 32 >> s;
        float od = __shfl_xor(bd, off);
        int   oi = __shfl_xor(bi, off);
        if (od < bd || (od == bd && oi < bi)) { bd = od; bi = oi; }
      }
      if (vd == bd && vi == bi) { vd = INFINITY; vi = 0x7fffffff; }
      if (lane == r) { myD = bd; myI = bi; }
    }

    int valid = (lane < K) && (myD < INFINITY) && (myI < N);
    float dist = sqrtf(fmaxf(myD, 0.f));
    int lab = labels[(valid && myI < N) ? myI : 0];
    int isz = (valid && dist == 0.f) ? 1 : 0;
    float wgt = 1.f / dist;

    float accw[NCLS]; float acci[NCLS]; int anyInf = 0;
    #pragma unroll
    for (int c = 0; c < NCLS; ++c) { accw[c] = 0.f; acci[c] = 0.f; }
    for (int r = 0; r < K; ++r) {
      int   vr   = __shfl(valid, r);
      int   labr = __shfl(lab, r);
      float wgtr = __shfl(wgt, r);
      int   iszr = __shfl(isz, r);
      if (vr) {
        anyInf |= iszr;
        #pragma unroll
        for (int c = 0; c < NCLS; ++c) {
          accw[c] += (labr == c) ? wgtr : 0.f;
          acci[c] += (labr == c && iszr) ? 1.f : 0.f;
        }
      }
    }

    if (lane == 0) {
      float proba[NCLS]; float s = 0.f;
      #pragma unroll
      for (int c = 0; c < NCLS; ++c) { proba[c] = anyInf ? acci[c] : accw[c]; s += proba[c]; }
      if (s == 0.f) s = 1.f;
      #pragma unroll
      for (int c = 0; c < NCLS; ++c) proba[c] = proba[c] / s;
      int best = 0; float bv = proba[0];
      #pragma unroll
      for (int c = 1; c < NCLS; ++c) if (proba[c] > bv) { bv = proba[c]; best = c; }
      out[q] = (float)best;
      #pragma unroll
      for (int c = 0; c < NCLS; ++c) out[B + q * NCLS + c] = proba[c];
    }
  }
}

extern "C" void kernel_launch(void* const* d_in, const int* in_sizes, int n_in,
                              void* d_out, int out_size, void* d_ws, size_t ws_size,
                              hipStream_t stream)
{
  const float* x      = (const float*)d_in[0];
  const float* train  = (const float*)d_in[1];
  const int*   labels = (const int*)d_in[2];
  float* out = (float*)d_out;

  const int B = in_sizes[0] / D;   // 1024
  const int N = in_sizes[2];       // 100000

  // workspace carve (16B-aligned), ~29 MB; samp ALIASES cand2 (sample/theta
  // complete before filter writes cand2 -- stream-ordered).
  char* ws = (char*)d_ws;
  size_t off = 0;
  ushort_t* train_bf = (ushort_t*)(ws + off); off += (size_t)NPAD * D * 2;           // 12.85 MB
  float*    t2       = (float*)(ws + off);    off += (size_t)NPAD * 4;               // 402 KB
  float*    nt2h     = (float*)(ws + off);    off += (size_t)NPAD * 4;               // 402 KB
  float*    theta    = (float*)(ws + off);    off += (size_t)B * 4;
  int*      cnts     = (int*)(ws + off);      off += (size_t)B * NCHUNK * 4;         // 459 KB
  int2*     cand2    = (int2*)(ws + off);     off += (size_t)B * NCHUNK * SLOT * 8;  // 14.7 MB
  float*    samp     = (float*)cand2;         // B*NSUB*16*4 = 4 MB <= cand2 region

  cvt_train<<<(NPAD * 4 + 255) / 256, 256, 0, stream>>>(train, train_bf, t2, nt2h, N);
  knn_sample<<<dim3(B / 64, NSUB), 256, 0, stream>>>(train_bf, x, nt2h, samp);
  knn_theta<<<(B + 3) / 4, 256, 0, stream>>>(samp, theta, B);
  knn_filter<<<dim3(16, NCHUNK), 256, 0, stream>>>(train_bf, x, nt2h, theta, cnts, cand2);
  knn_vote<<<B, 256, 0, stream>>>(x, train, t2, labels, cnts, cand2, out, B, N);
}